// Round 17
// baseline (170.676 us; speedup 1.0000x reference)
//
#include <hip/hip_runtime.h>
#include <hip/hip_bf16.h>
#include <math.h>

constexpr int HS = 32;      // half spatial (32x32 grids)
constexpr int Lq = 1024;    // HS*HS
constexpr int CN = 128;     // channels
// batches = 2. Inputs fp32 (f, b, mask). Output fp32 (r11-verified).
// R17: launch consolidation — prep+wm merged; fuse12+softmax fused (S2T eliminated).
// All arithmetic bit-identical to r16 (absmax 0.015625 expected).

typedef short bf16x8 __attribute__((ext_vector_type(8)));
typedef float f32x4  __attribute__((ext_vector_type(4)));

__device__ inline unsigned short f2bf(float x) {   // RNE float->bf16 bits
    union { float f; unsigned int u; } c; c.f = x;
    return (unsigned short)((c.u + 0x7FFF + ((c.u >> 16) & 1)) >> 16);
}
__device__ inline float bf2f(unsigned short h) {
    union { unsigned int u; float f; } c; c.u = ((unsigned int)h) << 16;
    return c.f;
}

// ---------------- merged prep+ssq+wm: one launch, two grid segments ----------------
// blocks [0,512): downsample + hi/lo bf16 splits + row ssq (4 rows/block, 64 lanes each)
// blocks [512, 16896): Wm gather (idx over 2*2048*1024)
__global__ __launch_bounds__(256) void k_prep3(const float* __restrict__ f,
                                               const float* __restrict__ bsrc,
                                               unsigned short* __restrict__ fH, unsigned short* __restrict__ fL,
                                               unsigned short* __restrict__ bH, unsigned short* __restrict__ bL,
                                               float* __restrict__ ssq,
                                               unsigned short* __restrict__ Wm) {
    int tx = threadIdx.x;
    if (blockIdx.x < 512) {
        int u = blockIdx.x * 4 + (tx >> 6);  // 0..2047 = bb*1024 + p
        int lane = tx & 63;
        int p = u & (Lq - 1), bb = u >> 10;
        int py = p >> 5, px = p & 31;
        long srcbase = (((long)bb * CN) * 64 + 2 * py) * 64 + 2 * px;
        float s = 0.f;
#pragma unroll
        for (int i = 0; i < 2; ++i) {
            int c = lane + i * 64;
            long src = srcbase + (long)c * 4096;
            float fv = f[src], bv = bsrc[src];
            int o = u * CN + c;
            unsigned short fh = f2bf(fv), bh = f2bf(bv);
            fH[o] = fh; fL[o] = f2bf(fv - bf2f(fh));
            bH[o] = bh; bL[o] = f2bf(bv - bf2f(bh));
            s += bv * bv;
        }
        for (int off = 32; off > 0; off >>= 1) s += __shfl_down(s, off, 64);
        if (lane == 0) ssq[u] = s;
    } else {
        int idx = (blockIdx.x - 512) * 256 + tx;   // 2*2048*1024
        int q  = idx & (Lq - 1);
        int m  = (idx >> 10) & 2047;
        int bb = idx >> 21;
        int c = m >> 4, u = (m >> 2) & 3, v = m & 3;
        int qy = q >> 5, qx = q & 31;
        int y = 2 * qy + u - 1, x = 2 * qx + v - 1;
        float val = 0.f;
        if ((unsigned)y < 64u && (unsigned)x < 64u)
            val = bsrc[(((long)bb * CN + c) * 64 + y) * 64 + x];
        Wm[idx] = f2bf(val);
    }
}

// ---------------- merged norms+mm ----------------
__global__ __launch_bounds__(256) void k_nm(const float* __restrict__ ssq, const float* __restrict__ mask,
                                            float* __restrict__ norms, float* __restrict__ mmb) {
    int idx = blockIdx.x * 256 + threadIdx.x;   // 0..3071
    if (idx < 2048) {
        int q = idx & (Lq - 1);
        int bb = idx >> 10;
        int qy = q >> 5, qx = q & 31;
        float s = 0.1152f;
        for (int dk = -1; dk <= 1; ++dk) {
            int y = qy + dk; if ((unsigned)y >= (unsigned)HS) continue;
            for (int dl = -1; dl <= 1; ++dl) {
                int x = qx + dl; if ((unsigned)x >= (unsigned)HS) continue;
                s += ssq[bb * Lq + y * HS + x];
            }
        }
        norms[idx] = sqrtf(s);
    } else {
        int q = idx - 2048;                      // 0..1023
        int qy = q >> 5, qx = q & 31;
        float s = 0.f;
        for (int dk = -1; dk <= 1; ++dk) {
            int y = qy + dk; if ((unsigned)y >= (unsigned)HS) continue;
            for (int dl = -1; dl <= 1; ++dl) {
                int x = qx + dl; if ((unsigned)x >= (unsigned)HS) continue;
                s += mask[(8 * y) * 256 + 8 * x];
            }
        }
        mmb[q] = (s == 0.0f) ? 1.0f : 0.0f;
    }
}

// ---------------- Gram MFMA bf16x2: GT[p'][q'] = sum_c fd[p'][c]*bd[q'][c] (r14-verified) ----------------
__global__ __launch_bounds__(256) void k_gram(const unsigned short* __restrict__ fH,
                                              const unsigned short* __restrict__ fL,
                                              const unsigned short* __restrict__ bH,
                                              const unsigned short* __restrict__ bL,
                                              float* __restrict__ GT) {
    const long bz = blockIdx.z;
    const unsigned short* AH = fH + bz * 131072;
    const unsigned short* AL = fL + bz * 131072;
    const unsigned short* BH = bH + bz * 131072;
    const unsigned short* BL = bL + bz * 131072;
    float* C = GT + (bz << 20);
    int t = threadIdx.x, w = t >> 6, lane = t & 63, quad = lane >> 4, l16 = lane & 15;
    int wm = blockIdx.x * 64 + (w & 1) * 32;
    int wn = blockIdx.y * 64 + (w >> 1) * 32;
    int ko = quad * 8;
    f32x4 acc[2][2] = {};
#pragma unroll
    for (int k0 = 0; k0 < 128; k0 += 32) {
        bf16x8 ah0 = *(const bf16x8*)&AH[(wm + l16) * 128 + ko + k0];
        bf16x8 ah1 = *(const bf16x8*)&AH[(wm + 16 + l16) * 128 + ko + k0];
        bf16x8 al0 = *(const bf16x8*)&AL[(wm + l16) * 128 + ko + k0];
        bf16x8 al1 = *(const bf16x8*)&AL[(wm + 16 + l16) * 128 + ko + k0];
        bf16x8 bh0 = *(const bf16x8*)&BH[(wn + l16) * 128 + ko + k0];
        bf16x8 bh1 = *(const bf16x8*)&BH[(wn + 16 + l16) * 128 + ko + k0];
        bf16x8 bl0 = *(const bf16x8*)&BL[(wn + l16) * 128 + ko + k0];
        bf16x8 bl1 = *(const bf16x8*)&BL[(wn + 16 + l16) * 128 + ko + k0];
        acc[0][0] = __builtin_amdgcn_mfma_f32_16x16x32_bf16(ah0, bh0, acc[0][0], 0, 0, 0);
        acc[0][1] = __builtin_amdgcn_mfma_f32_16x16x32_bf16(ah0, bh1, acc[0][1], 0, 0, 0);
        acc[1][0] = __builtin_amdgcn_mfma_f32_16x16x32_bf16(ah1, bh0, acc[1][0], 0, 0, 0);
        acc[1][1] = __builtin_amdgcn_mfma_f32_16x16x32_bf16(ah1, bh1, acc[1][1], 0, 0, 0);
        acc[0][0] = __builtin_amdgcn_mfma_f32_16x16x32_bf16(ah0, bl0, acc[0][0], 0, 0, 0);
        acc[0][1] = __builtin_amdgcn_mfma_f32_16x16x32_bf16(ah0, bl1, acc[0][1], 0, 0, 0);
        acc[1][0] = __builtin_amdgcn_mfma_f32_16x16x32_bf16(ah1, bl0, acc[1][0], 0, 0, 0);
        acc[1][1] = __builtin_amdgcn_mfma_f32_16x16x32_bf16(ah1, bl1, acc[1][1], 0, 0, 0);
        acc[0][0] = __builtin_amdgcn_mfma_f32_16x16x32_bf16(al0, bh0, acc[0][0], 0, 0, 0);
        acc[0][1] = __builtin_amdgcn_mfma_f32_16x16x32_bf16(al0, bh1, acc[0][1], 0, 0, 0);
        acc[1][0] = __builtin_amdgcn_mfma_f32_16x16x32_bf16(al1, bh0, acc[1][0], 0, 0, 0);
        acc[1][1] = __builtin_amdgcn_mfma_f32_16x16x32_bf16(al1, bh1, acc[1][1], 0, 0, 0);
    }
#pragma unroll
    for (int i = 0; i < 2; ++i)
#pragma unroll
        for (int j = 0; j < 2; ++j) {
            int mrow = wm + i * 16 + quad * 4;
            int ncol = wn + j * 16 + l16;
#pragma unroll
            for (int r = 0; r < 4; ++r)
                C[(long)(mrow + r) * Lq + ncol] = acc[i][j][r];
        }
}

// ---------------- S0T[p][q] = band9(GT) / norms[q]  (T-layout, r14-verified) ----------------
__global__ __launch_bounds__(256) void k_s0T(const float* __restrict__ GT, const float* __restrict__ norms,
                                             float* __restrict__ S0T) {
    int idx = blockIdx.x * 256 + threadIdx.x;  // 2*1024*1024
    int q  = idx & (Lq - 1);
    int pp = (idx >> 10) & (Lq - 1);
    int bb = idx >> 20;
    int qy = q >> 5, qx = q & 31, py = pp >> 5, px = pp & 31;
    const float* Gb = GT + ((long)bb << 20);
    float s = 0.f;
#pragma unroll
    for (int dk = -1; dk <= 1; ++dk) {
        if ((unsigned)(qy + dk) >= (unsigned)HS || (unsigned)(py + dk) >= (unsigned)HS) continue;
#pragma unroll
        for (int dl = -1; dl <= 1; ++dl) {
            if ((unsigned)(qx + dl) >= (unsigned)HS || (unsigned)(px + dl) >= (unsigned)HS) continue;
            int sft = dk * HS + dl;
            s += Gb[(long)(pp + sft) * Lq + (q + sft)];
        }
    }
    S0T[idx] = s / norms[bb * Lq + q];
}

// ---------------- FUSED fuse12 + softmax: S0T -> attnT bf16, S2T never materialized ----------------
// Wave per output row (bb,P). Per lane: 16 cols Q = i*64+lane; fuse gather arithmetic
// identical to r16's k_fuse12 (same taps, same order), then r16's softmax in-register.
__global__ __launch_bounds__(256) void k_fsm(const float* __restrict__ S0T, const float* __restrict__ mmb,
                                             unsigned short* __restrict__ At) {
    int wid = blockIdx.x * 4 + (threadIdx.x >> 6);   // 0..2047
    int lane = threadIdx.x & 63;
    int bb = wid >> 10, P = wid & (Lq - 1);
    const float* S = S0T + ((long)bb << 20);
    unsigned short* orow = At + ((long)bb << 20) + (long)P * Lq;
    int hb = P >> 5, wb = P & 31;
    int ip = wb * HS + hb;
    float x[16]; float mx = -1e30f;
#pragma unroll
    for (int i = 0; i < 16; ++i) {
        int Q = i * 64 + lane;
        int hf = Q >> 5, wf = Q & 31;
        int jp = wf * HS + hf;
        float s = 0.f;
#pragma unroll
        for (int d = -1; d <= 1; ++d) {
            int t = ip + d, r = jp + d;
            if ((unsigned)t < (unsigned)Lq && (unsigned)r < (unsigned)Lq) {
                int q2 = (t & 31) * HS + (t >> 5);
                int p2 = (r & 31) * HS + (r >> 5);
                long base = (long)q2 * Lq + p2;
                float v = S[base];
                if (q2 > 0 && p2 > 0)             v += S[base - (Lq + 1)];
                if (q2 < Lq - 1 && p2 < Lq - 1)   v += S[base + (Lq + 1)];
                s += v;
            }
        }
        x[i] = s * mmb[Q] * 10.0f;
        mx = fmaxf(mx, x[i]);
    }
    for (int off = 32; off > 0; off >>= 1) mx = fmaxf(mx, __shfl_xor(mx, off, 64));
    float e[16]; float sum = 0.f;
#pragma unroll
    for (int i = 0; i < 16; ++i) { e[i] = __expf(x[i] - mx); sum += e[i]; }
    for (int off = 32; off > 0; off >>= 1) sum += __shfl_xor(sum, off, 64);
    float inv = 1.0f / sum;
#pragma unroll
    for (int i = 0; i < 16; ++i) {
        int Q = i * 64 + lane;
        orow[Q] = f2bf(e[i] * mmb[Q] * inv);
    }
}

// ---------------- MFMA GEMM, B-only LDS: P[m][p] = sum_q Wm[m][q]*attnT[p][q] (r16-verified) ----------------
__global__ __launch_bounds__(256) void k_gemm_mfma(const unsigned short* __restrict__ WmA,
                                                   const unsigned short* __restrict__ At,
                                                   float* __restrict__ Cm) {
    const long bz = blockIdx.z;
    const unsigned short* A = WmA + bz * (2048L * Lq);
    const unsigned short* B = At  + bz * ((long)Lq * Lq);
    float* C = Cm + bz * (2048L * Lq);
    __shared__ __align__(16) unsigned short Bs[4096];
    int t = threadIdx.x;
    int w = t >> 6, lane = t & 63;
    int quad = lane >> 4, l16 = lane & 15;
    int m0 = blockIdx.x * 64, n0 = blockIdx.y * 64;
    const unsigned short* aS = A + (long)(m0 + w * 16 + l16) * Lq + quad * 8;
    const unsigned short* bS = B + (long)(n0 + w * 16 + l16) * Lq + quad * 8;
    int sidx = w * 512 + quad * 128 + l16 * 8;
    int fidx = quad * 128 + l16 * 8;
    f32x4 acc0 = {0,0,0,0}, acc1 = {0,0,0,0}, acc2 = {0,0,0,0}, acc3 = {0,0,0,0};
    for (int k0 = 0; k0 < Lq; k0 += 64) {
        bf16x8 bv0 = *(const bf16x8*)(bS + k0);
        bf16x8 bv1 = *(const bf16x8*)(bS + k0 + 32);
        bf16x8 af0 = *(const bf16x8*)(aS + k0);        // A: direct, no LDS
        bf16x8 af1 = *(const bf16x8*)(aS + k0 + 32);
        __syncthreads();
        *(bf16x8*)&Bs[sidx]        = bv0;
        *(bf16x8*)&Bs[2048 + sidx] = bv1;
        __syncthreads();
#pragma unroll
        for (int kc = 0; kc < 2; ++kc) {
            int o = kc * 2048;
            bf16x8 af = kc ? af1 : af0;
            bf16x8 b0 = *(const bf16x8*)&Bs[o + fidx];
            bf16x8 b1 = *(const bf16x8*)&Bs[o + 512 + fidx];
            bf16x8 b2 = *(const bf16x8*)&Bs[o + 1024 + fidx];
            bf16x8 b3 = *(const bf16x8*)&Bs[o + 1536 + fidx];
            acc0 = __builtin_amdgcn_mfma_f32_16x16x32_bf16(af, b0, acc0, 0, 0, 0);
            acc1 = __builtin_amdgcn_mfma_f32_16x16x32_bf16(af, b1, acc1, 0, 0, 0);
            acc2 = __builtin_amdgcn_mfma_f32_16x16x32_bf16(af, b2, acc2, 0, 0, 0);
            acc3 = __builtin_amdgcn_mfma_f32_16x16x32_bf16(af, b3, acc3, 0, 0, 0);
        }
    }
    int mrow = m0 + w * 16 + quad * 4;
#pragma unroll
    for (int r = 0; r < 4; ++r) {
        C[(long)(mrow + r) * Lq + n0 +  0 + l16] = acc0[r];
        C[(long)(mrow + r) * Lq + n0 + 16 + l16] = acc1[r];
        C[(long)(mrow + r) * Lq + n0 + 32 + l16] = acc2[r];
        C[(long)(mrow + r) * Lq + n0 + 48 + l16] = acc3[r];
    }
}

// ---------------- literal conv epilogue: fp32 tap-sum, /4, store fp32 (r11-verified) ----------------
__global__ __launch_bounds__(256) void k_epi2(const float* __restrict__ P, float* __restrict__ out) {
    int idx = blockIdx.x * 256 + threadIdx.x;   // 1048576
    int ox = idx & 63, oy = (idx >> 6) & 63, c = (idx >> 12) & 127, bb = idx >> 19;
    const float* Pb = P + (long)bb * 2048 * Lq;
    float s = 0.f;
#pragma unroll
    for (int u = 0; u < 4; ++u) {
        int t = oy + u - 2;
        if (t & 1) continue;
        int iy = t >> 1;
        if ((unsigned)iy >= (unsigned)HS) continue;
#pragma unroll
        for (int v = 0; v < 4; ++v) {
            int r = ox + v - 2;
            if (r & 1) continue;
            int ix = r >> 1;
            if ((unsigned)ix >= (unsigned)HS) continue;
            s += Pb[(long)((c << 4) + (3 - u) * 4 + (3 - v)) * Lq + (iy << 5) + ix];
        }
    }
    out[idx] = 0.25f * s;
}

extern "C" void kernel_launch(void* const* d_in, const int* in_sizes, int n_in,
                              void* d_out, int out_size, void* d_ws, size_t ws_size,
                              hipStream_t stream) {
    const float* f    = (const float*)d_in[0];
    const float* bsrc = (const float*)d_in[1];
    const float* mask = (const float*)d_in[2];
    float* out = (float*)d_out;
    float* ws = (float*)d_ws;

    // workspace (floats): ~7.9M = 31.5 MB
    float* ssq   = ws;                        // 2048
    float* norms = ssq   + 2048;              // 2048
    float* mmb   = norms + 2048;              // 1024
    unsigned short* fH = (unsigned short*)(mmb + 1024);      // 262144 ushorts each
    unsigned short* fL = fH + 262144;
    unsigned short* bH = fL + 262144;
    unsigned short* bL = bH + 262144;
    float* GTa   = (float*)(bL + 262144);     // 2097152 : GT -> attnT(bf16)
    float* C1    = GTa + 2097152;             // 2097152 : S0T -> P[0:2M]
    float* C2    = C1  + 2097152;             // 2097152 : P[2M:4M]
    unsigned short* Wm = (unsigned short*)(C2 + 2097152);    // 4194304 ushorts
    float* S0T  = C1;
    unsigned short* attnT = (unsigned short*)GTa;  // GT dead after k_s0T
    float* P    = C1;      // spans C1+C2; S0T dead after k_fsm

    hipLaunchKernelGGL(k_prep3,     dim3(16896),      dim3(256), 0, stream, f, bsrc, fH, fL, bH, bL, ssq, Wm);
    hipLaunchKernelGGL(k_nm,        dim3(12),         dim3(256), 0, stream, ssq, mask, norms, mmb);
    hipLaunchKernelGGL(k_gram,      dim3(16, 16, 2),  dim3(256), 0, stream, fH, fL, bH, bL, GTa);
    hipLaunchKernelGGL(k_s0T,       dim3(8192),       dim3(256), 0, stream, GTa, norms, S0T);
    hipLaunchKernelGGL(k_fsm,       dim3(512),        dim3(256), 0, stream, S0T, mmb, attnT);
    hipLaunchKernelGGL(k_gemm_mfma, dim3(32, 16, 2),  dim3(256), 0, stream, Wm, attnT, P);
    hipLaunchKernelGGL(k_epi2,      dim3(4096),       dim3(256), 0, stream, P, out);
}

// Round 18
// 155.370 us; speedup vs baseline: 1.0985x; 1.0985x over previous
//
#include <hip/hip_runtime.h>
#include <hip/hip_bf16.h>
#include <math.h>

constexpr int HS = 32;      // half spatial (32x32 grids)
constexpr int Lq = 1024;    // HS*HS
constexpr int CN = 128;     // channels
// batches = 2. Inputs fp32 (f, b, mask). Output fp32 (r11-verified).
// R18: revert r17's fuse12+softmax mega-kernel (over-fusion regression: 8 waves/CU
// couldn't hide the 27-tap gather; separate coalesced passes were L2-BW-efficient).
// Keep prep+wm merge. Structure = r16 + prep3. Arithmetic bit-identical (0.015625).

typedef short bf16x8 __attribute__((ext_vector_type(8)));
typedef float f32x4  __attribute__((ext_vector_type(4)));

__device__ inline unsigned short f2bf(float x) {   // RNE float->bf16 bits
    union { float f; unsigned int u; } c; c.f = x;
    return (unsigned short)((c.u + 0x7FFF + ((c.u >> 16) & 1)) >> 16);
}
__device__ inline float bf2f(unsigned short h) {
    union { unsigned int u; float f; } c; c.u = ((unsigned int)h) << 16;
    return c.f;
}

// ---------------- merged prep+ssq+wm: one launch, two grid segments ----------------
__global__ __launch_bounds__(256) void k_prep3(const float* __restrict__ f,
                                               const float* __restrict__ bsrc,
                                               unsigned short* __restrict__ fH, unsigned short* __restrict__ fL,
                                               unsigned short* __restrict__ bH, unsigned short* __restrict__ bL,
                                               float* __restrict__ ssq,
                                               unsigned short* __restrict__ Wm) {
    int tx = threadIdx.x;
    if (blockIdx.x < 512) {
        int u = blockIdx.x * 4 + (tx >> 6);  // 0..2047 = bb*1024 + p
        int lane = tx & 63;
        int p = u & (Lq - 1), bb = u >> 10;
        int py = p >> 5, px = p & 31;
        long srcbase = (((long)bb * CN) * 64 + 2 * py) * 64 + 2 * px;
        float s = 0.f;
#pragma unroll
        for (int i = 0; i < 2; ++i) {
            int c = lane + i * 64;
            long src = srcbase + (long)c * 4096;
            float fv = f[src], bv = bsrc[src];
            int o = u * CN + c;
            unsigned short fh = f2bf(fv), bh = f2bf(bv);
            fH[o] = fh; fL[o] = f2bf(fv - bf2f(fh));
            bH[o] = bh; bL[o] = f2bf(bv - bf2f(bh));
            s += bv * bv;
        }
        for (int off = 32; off > 0; off >>= 1) s += __shfl_down(s, off, 64);
        if (lane == 0) ssq[u] = s;
    } else {
        int idx = (blockIdx.x - 512) * 256 + tx;   // 2*2048*1024
        int q  = idx & (Lq - 1);
        int m  = (idx >> 10) & 2047;
        int bb = idx >> 21;
        int c = m >> 4, u = (m >> 2) & 3, v = m & 3;
        int qy = q >> 5, qx = q & 31;
        int y = 2 * qy + u - 1, x = 2 * qx + v - 1;
        float val = 0.f;
        if ((unsigned)y < 64u && (unsigned)x < 64u)
            val = bsrc[(((long)bb * CN + c) * 64 + y) * 64 + x];
        Wm[idx] = f2bf(val);
    }
}

// ---------------- merged norms+mm ----------------
__global__ __launch_bounds__(256) void k_nm(const float* __restrict__ ssq, const float* __restrict__ mask,
                                            float* __restrict__ norms, float* __restrict__ mmb) {
    int idx = blockIdx.x * 256 + threadIdx.x;   // 0..3071
    if (idx < 2048) {
        int q = idx & (Lq - 1);
        int bb = idx >> 10;
        int qy = q >> 5, qx = q & 31;
        float s = 0.1152f;
        for (int dk = -1; dk <= 1; ++dk) {
            int y = qy + dk; if ((unsigned)y >= (unsigned)HS) continue;
            for (int dl = -1; dl <= 1; ++dl) {
                int x = qx + dl; if ((unsigned)x >= (unsigned)HS) continue;
                s += ssq[bb * Lq + y * HS + x];
            }
        }
        norms[idx] = sqrtf(s);
    } else {
        int q = idx - 2048;                      // 0..1023
        int qy = q >> 5, qx = q & 31;
        float s = 0.f;
        for (int dk = -1; dk <= 1; ++dk) {
            int y = qy + dk; if ((unsigned)y >= (unsigned)HS) continue;
            for (int dl = -1; dl <= 1; ++dl) {
                int x = qx + dl; if ((unsigned)x >= (unsigned)HS) continue;
                s += mask[(8 * y) * 256 + 8 * x];
            }
        }
        mmb[q] = (s == 0.0f) ? 1.0f : 0.0f;
    }
}

// ---------------- Gram MFMA bf16x2: GT[p'][q'] = sum_c fd[p'][c]*bd[q'][c] (r14-verified) ----------------
__global__ __launch_bounds__(256) void k_gram(const unsigned short* __restrict__ fH,
                                              const unsigned short* __restrict__ fL,
                                              const unsigned short* __restrict__ bH,
                                              const unsigned short* __restrict__ bL,
                                              float* __restrict__ GT) {
    const long bz = blockIdx.z;
    const unsigned short* AH = fH + bz * 131072;
    const unsigned short* AL = fL + bz * 131072;
    const unsigned short* BH = bH + bz * 131072;
    const unsigned short* BL = bL + bz * 131072;
    float* C = GT + (bz << 20);
    int t = threadIdx.x, w = t >> 6, lane = t & 63, quad = lane >> 4, l16 = lane & 15;
    int wm = blockIdx.x * 64 + (w & 1) * 32;
    int wn = blockIdx.y * 64 + (w >> 1) * 32;
    int ko = quad * 8;
    f32x4 acc[2][2] = {};
#pragma unroll
    for (int k0 = 0; k0 < 128; k0 += 32) {
        bf16x8 ah0 = *(const bf16x8*)&AH[(wm + l16) * 128 + ko + k0];
        bf16x8 ah1 = *(const bf16x8*)&AH[(wm + 16 + l16) * 128 + ko + k0];
        bf16x8 al0 = *(const bf16x8*)&AL[(wm + l16) * 128 + ko + k0];
        bf16x8 al1 = *(const bf16x8*)&AL[(wm + 16 + l16) * 128 + ko + k0];
        bf16x8 bh0 = *(const bf16x8*)&BH[(wn + l16) * 128 + ko + k0];
        bf16x8 bh1 = *(const bf16x8*)&BH[(wn + 16 + l16) * 128 + ko + k0];
        bf16x8 bl0 = *(const bf16x8*)&BL[(wn + l16) * 128 + ko + k0];
        bf16x8 bl1 = *(const bf16x8*)&BL[(wn + 16 + l16) * 128 + ko + k0];
        acc[0][0] = __builtin_amdgcn_mfma_f32_16x16x32_bf16(ah0, bh0, acc[0][0], 0, 0, 0);
        acc[0][1] = __builtin_amdgcn_mfma_f32_16x16x32_bf16(ah0, bh1, acc[0][1], 0, 0, 0);
        acc[1][0] = __builtin_amdgcn_mfma_f32_16x16x32_bf16(ah1, bh0, acc[1][0], 0, 0, 0);
        acc[1][1] = __builtin_amdgcn_mfma_f32_16x16x32_bf16(ah1, bh1, acc[1][1], 0, 0, 0);
        acc[0][0] = __builtin_amdgcn_mfma_f32_16x16x32_bf16(ah0, bl0, acc[0][0], 0, 0, 0);
        acc[0][1] = __builtin_amdgcn_mfma_f32_16x16x32_bf16(ah0, bl1, acc[0][1], 0, 0, 0);
        acc[1][0] = __builtin_amdgcn_mfma_f32_16x16x32_bf16(ah1, bl0, acc[1][0], 0, 0, 0);
        acc[1][1] = __builtin_amdgcn_mfma_f32_16x16x32_bf16(ah1, bl1, acc[1][1], 0, 0, 0);
        acc[0][0] = __builtin_amdgcn_mfma_f32_16x16x32_bf16(al0, bh0, acc[0][0], 0, 0, 0);
        acc[0][1] = __builtin_amdgcn_mfma_f32_16x16x32_bf16(al0, bh1, acc[0][1], 0, 0, 0);
        acc[1][0] = __builtin_amdgcn_mfma_f32_16x16x32_bf16(al1, bh0, acc[1][0], 0, 0, 0);
        acc[1][1] = __builtin_amdgcn_mfma_f32_16x16x32_bf16(al1, bh1, acc[1][1], 0, 0, 0);
    }
#pragma unroll
    for (int i = 0; i < 2; ++i)
#pragma unroll
        for (int j = 0; j < 2; ++j) {
            int mrow = wm + i * 16 + quad * 4;
            int ncol = wn + j * 16 + l16;
#pragma unroll
            for (int r = 0; r < 4; ++r)
                C[(long)(mrow + r) * Lq + ncol] = acc[i][j][r];
        }
}

// ---------------- S0T[p][q] = band9(GT) / norms[q]  (T-layout, r14-verified) ----------------
__global__ __launch_bounds__(256) void k_s0T(const float* __restrict__ GT, const float* __restrict__ norms,
                                             float* __restrict__ S0T) {
    int idx = blockIdx.x * 256 + threadIdx.x;  // 2*1024*1024
    int q  = idx & (Lq - 1);
    int pp = (idx >> 10) & (Lq - 1);
    int bb = idx >> 20;
    int qy = q >> 5, qx = q & 31, py = pp >> 5, px = pp & 31;
    const float* Gb = GT + ((long)bb << 20);
    float s = 0.f;
#pragma unroll
    for (int dk = -1; dk <= 1; ++dk) {
        if ((unsigned)(qy + dk) >= (unsigned)HS || (unsigned)(py + dk) >= (unsigned)HS) continue;
#pragma unroll
        for (int dl = -1; dl <= 1; ++dl) {
            if ((unsigned)(qx + dl) >= (unsigned)HS || (unsigned)(px + dl) >= (unsigned)HS) continue;
            int sft = dk * HS + dl;
            s += Gb[(long)(pp + sft) * Lq + (q + sft)];
        }
    }
    S0T[idx] = s / norms[bb * Lq + q];
}

// ---------------- FUSED fuse1+fuse2 on T layout (r14/r16-verified) ----------------
__global__ __launch_bounds__(256) void k_fuse12(const float* __restrict__ S0, float* __restrict__ S2) {
    int idx = blockIdx.x * 256 + threadIdx.x;   // 2*1024*1024
    int p  = idx & (Lq - 1);
    int q  = (idx >> 10) & (Lq - 1);
    int bb = idx >> 20;
    int hb = q >> 5, wb = q & 31, hf = p >> 5, wf = p & 31;
    int ip = wb * HS + hb, jp = wf * HS + hf;
    const float* S = S0 + (long)bb * Lq * Lq;
    float s = 0.f;
#pragma unroll
    for (int d = -1; d <= 1; ++d) {
        int t = ip + d, r = jp + d;
        if ((unsigned)t < (unsigned)Lq && (unsigned)r < (unsigned)Lq) {
            int q2 = (t & 31) * HS + (t >> 5);
            int p2 = (r & 31) * HS + (r >> 5);
            long base = (long)q2 * Lq + p2;
            float v = S[base];
            if (q2 > 0 && p2 > 0)             v += S[base - (Lq + 1)];
            if (q2 < Lq - 1 && p2 < Lq - 1)   v += S[base + (Lq + 1)];
            s += v;
        }
    }
    S2[idx] = s;
}

// ---------------- row softmax over q on S2T[p][q]; writes attnT bf16 [p][q] (r13-verified) ----------------
__global__ __launch_bounds__(256) void k_softmaxT(const float* __restrict__ S2T, const float* __restrict__ mmb,
                                                  unsigned short* __restrict__ At) {
    int wid = blockIdx.x * 4 + (threadIdx.x >> 6);   // 0..2047
    int lane = threadIdx.x & 63;
    int bb = wid >> 10, p = wid & (Lq - 1);
    const float* row = S2T + ((long)bb << 20) + (long)p * Lq;
    unsigned short* orow = At + ((long)bb << 20) + (long)p * Lq;
    float x[16]; float mx = -1e30f;
#pragma unroll
    for (int i = 0; i < 16; ++i) {
        int q = i * 64 + lane;
        x[i] = row[q] * mmb[q] * 10.0f;
        mx = fmaxf(mx, x[i]);
    }
    for (int off = 32; off > 0; off >>= 1) mx = fmaxf(mx, __shfl_xor(mx, off, 64));
    float e[16]; float s = 0.f;
#pragma unroll
    for (int i = 0; i < 16; ++i) { e[i] = __expf(x[i] - mx); s += e[i]; }
    for (int off = 32; off > 0; off >>= 1) s += __shfl_xor(s, off, 64);
    float inv = 1.0f / s;
#pragma unroll
    for (int i = 0; i < 16; ++i) {
        int q = i * 64 + lane;
        orow[q] = f2bf(e[i] * mmb[q] * inv);
    }
}

// ---------------- MFMA GEMM, B-only LDS: P[m][p] = sum_q Wm[m][q]*attnT[p][q] (r16-verified) ----------------
__global__ __launch_bounds__(256) void k_gemm_mfma(const unsigned short* __restrict__ WmA,
                                                   const unsigned short* __restrict__ At,
                                                   float* __restrict__ Cm) {
    const long bz = blockIdx.z;
    const unsigned short* A = WmA + bz * (2048L * Lq);
    const unsigned short* B = At  + bz * ((long)Lq * Lq);
    float* C = Cm + bz * (2048L * Lq);
    __shared__ __align__(16) unsigned short Bs[4096];
    int t = threadIdx.x;
    int w = t >> 6, lane = t & 63;
    int quad = lane >> 4, l16 = lane & 15;
    int m0 = blockIdx.x * 64, n0 = blockIdx.y * 64;
    const unsigned short* aS = A + (long)(m0 + w * 16 + l16) * Lq + quad * 8;
    const unsigned short* bS = B + (long)(n0 + w * 16 + l16) * Lq + quad * 8;
    int sidx = w * 512 + quad * 128 + l16 * 8;
    int fidx = quad * 128 + l16 * 8;
    f32x4 acc0 = {0,0,0,0}, acc1 = {0,0,0,0}, acc2 = {0,0,0,0}, acc3 = {0,0,0,0};
    for (int k0 = 0; k0 < Lq; k0 += 64) {
        bf16x8 bv0 = *(const bf16x8*)(bS + k0);
        bf16x8 bv1 = *(const bf16x8*)(bS + k0 + 32);
        bf16x8 af0 = *(const bf16x8*)(aS + k0);        // A: direct, no LDS
        bf16x8 af1 = *(const bf16x8*)(aS + k0 + 32);
        __syncthreads();
        *(bf16x8*)&Bs[sidx]        = bv0;
        *(bf16x8*)&Bs[2048 + sidx] = bv1;
        __syncthreads();
#pragma unroll
        for (int kc = 0; kc < 2; ++kc) {
            int o = kc * 2048;
            bf16x8 af = kc ? af1 : af0;
            bf16x8 b0 = *(const bf16x8*)&Bs[o + fidx];
            bf16x8 b1 = *(const bf16x8*)&Bs[o + 512 + fidx];
            bf16x8 b2 = *(const bf16x8*)&Bs[o + 1024 + fidx];
            bf16x8 b3 = *(const bf16x8*)&Bs[o + 1536 + fidx];
            acc0 = __builtin_amdgcn_mfma_f32_16x16x32_bf16(af, b0, acc0, 0, 0, 0);
            acc1 = __builtin_amdgcn_mfma_f32_16x16x32_bf16(af, b1, acc1, 0, 0, 0);
            acc2 = __builtin_amdgcn_mfma_f32_16x16x32_bf16(af, b2, acc2, 0, 0, 0);
            acc3 = __builtin_amdgcn_mfma_f32_16x16x32_bf16(af, b3, acc3, 0, 0, 0);
        }
    }
    int mrow = m0 + w * 16 + quad * 4;
#pragma unroll
    for (int r = 0; r < 4; ++r) {
        C[(long)(mrow + r) * Lq + n0 +  0 + l16] = acc0[r];
        C[(long)(mrow + r) * Lq + n0 + 16 + l16] = acc1[r];
        C[(long)(mrow + r) * Lq + n0 + 32 + l16] = acc2[r];
        C[(long)(mrow + r) * Lq + n0 + 48 + l16] = acc3[r];
    }
}

// ---------------- literal conv epilogue: fp32 tap-sum, /4, store fp32 (r11-verified) ----------------
__global__ __launch_bounds__(256) void k_epi2(const float* __restrict__ P, float* __restrict__ out) {
    int idx = blockIdx.x * 256 + threadIdx.x;   // 1048576
    int ox = idx & 63, oy = (idx >> 6) & 63, c = (idx >> 12) & 127, bb = idx >> 19;
    const float* Pb = P + (long)bb * 2048 * Lq;
    float s = 0.f;
#pragma unroll
    for (int u = 0; u < 4; ++u) {
        int t = oy + u - 2;
        if (t & 1) continue;
        int iy = t >> 1;
        if ((unsigned)iy >= (unsigned)HS) continue;
#pragma unroll
        for (int v = 0; v < 4; ++v) {
            int r = ox + v - 2;
            if (r & 1) continue;
            int ix = r >> 1;
            if ((unsigned)ix >= (unsigned)HS) continue;
            s += Pb[(long)((c << 4) + (3 - u) * 4 + (3 - v)) * Lq + (iy << 5) + ix];
        }
    }
    out[idx] = 0.25f * s;
}

extern "C" void kernel_launch(void* const* d_in, const int* in_sizes, int n_in,
                              void* d_out, int out_size, void* d_ws, size_t ws_size,
                              hipStream_t stream) {
    const float* f    = (const float*)d_in[0];
    const float* bsrc = (const float*)d_in[1];
    const float* mask = (const float*)d_in[2];
    float* out = (float*)d_out;
    float* ws = (float*)d_ws;

    // workspace (floats): ~8.9M = 35.7 MB
    float* ssq   = ws;                        // 2048
    float* norms = ssq   + 2048;              // 2048
    float* mmb   = norms + 2048;              // 1024
    unsigned short* fH = (unsigned short*)(mmb + 1024);      // 262144 ushorts each
    unsigned short* fL = fH + 262144;
    unsigned short* bH = fL + 262144;
    unsigned short* bL = bH + 262144;
    float* GTa   = (float*)(bL + 262144);     // 2097152 : GT -> attnT(bf16)
    float* C1    = GTa + 2097152;             // 2097152 : S0T -> P[0:2M]
    float* C2    = C1  + 2097152;             // 2097152 : S2T -> P[2M:4M]
    unsigned short* Wm = (unsigned short*)(C2 + 2097152);    // 4194304 ushorts
    float* S0T  = C1;
    float* S2T  = C2;
    unsigned short* attnT = (unsigned short*)GTa;  // GT dead after k_s0T
    float* P    = C1;      // spans C1+C2; S0T dead after fuse12, S2T dead after softmax

    hipLaunchKernelGGL(k_prep3,     dim3(16896),      dim3(256), 0, stream, f, bsrc, fH, fL, bH, bL, ssq, Wm);
    hipLaunchKernelGGL(k_nm,        dim3(12),         dim3(256), 0, stream, ssq, mask, norms, mmb);
    hipLaunchKernelGGL(k_gram,      dim3(16, 16, 2),  dim3(256), 0, stream, fH, fL, bH, bL, GTa);
    hipLaunchKernelGGL(k_s0T,       dim3(8192),       dim3(256), 0, stream, GTa, norms, S0T);
    hipLaunchKernelGGL(k_fuse12,    dim3(8192),       dim3(256), 0, stream, S0T, S2T);
    hipLaunchKernelGGL(k_softmaxT,  dim3(512),        dim3(256), 0, stream, S2T, mmb, attnT);
    hipLaunchKernelGGL(k_gemm_mfma, dim3(32, 16, 2),  dim3(256), 0, stream, Wm, attnT, P);
    hipLaunchKernelGGL(k_epi2,      dim3(4096),       dim3(256), 0, stream, P, out);
}